// Round 1
// baseline (1104.674 us; speedup 1.0000x reference)
//
#include <hip/hip_runtime.h>
#include <math.h>

#define DIM 512
#define NH 8
#define HD 64
#define SS 2048
#define NB 2

// ---------------------------------------------------------------------------
// K1: QKV projection.  y = x @ W^T + b, scattered to [B, H, S, HD].
// fp32 tiled GEMM: BM=BN=64, BK=16, 256 threads, 4x4 microtile.
// ---------------------------------------------------------------------------
__global__ __launch_bounds__(256) void qkv_proj_kernel(
    const float* __restrict__ xq, const float* __restrict__ xk, const float* __restrict__ xv,
    const float* __restrict__ Wq, const float* __restrict__ bq,
    const float* __restrict__ Wk, const float* __restrict__ bk,
    const float* __restrict__ Wv, const float* __restrict__ bv,
    float* __restrict__ qh, float* __restrict__ kh, float* __restrict__ vh)
{
  const int which = blockIdx.z;
  const float* A    = (which == 0) ? xq : (which == 1) ? xk : xv;
  const float* W    = (which == 0) ? Wq : (which == 1) ? Wk : Wv;
  const float* bias = (which == 0) ? bq : (which == 1) ? bk : bv;
  float* out        = (which == 0) ? qh : (which == 1) ? kh : vh;

  __shared__ float As[16][68];  // [k][m], +4 pad keeps float4 reads aligned & conflict-light
  __shared__ float Bs[16][68];  // [k][n]

  const int m0 = blockIdx.x * 64;
  const int n0 = blockIdx.y * 64;
  const int tid = threadIdx.x;
  const int tr = tid >> 4;        // 0..15
  const int tc = tid & 15;        // 0..15
  const int lr = tid >> 2;        // 0..63 (load row)
  const int lk = (tid & 3) << 2;  // 0,4,8,12 (load k)

  float acc[4][4] = {};

  for (int k0 = 0; k0 < DIM; k0 += 16) {
    const float4 av = *(const float4*)&A[(m0 + lr) * DIM + k0 + lk];
    const float4 wv = *(const float4*)&W[(n0 + lr) * DIM + k0 + lk];
    As[lk + 0][lr] = av.x; As[lk + 1][lr] = av.y; As[lk + 2][lr] = av.z; As[lk + 3][lr] = av.w;
    Bs[lk + 0][lr] = wv.x; Bs[lk + 1][lr] = wv.y; Bs[lk + 2][lr] = wv.z; Bs[lk + 3][lr] = wv.w;
    __syncthreads();
#pragma unroll
    for (int kk = 0; kk < 16; ++kk) {
      const float4 a4 = *(const float4*)&As[kk][tr * 4];
      const float4 b4 = *(const float4*)&Bs[kk][tc * 4];
      const float a[4] = {a4.x, a4.y, a4.z, a4.w};
      const float b[4] = {b4.x, b4.y, b4.z, b4.w};
#pragma unroll
      for (int i = 0; i < 4; ++i)
#pragma unroll
        for (int j = 0; j < 4; ++j) acc[i][j] += a[i] * b[j];
    }
    __syncthreads();
  }

#pragma unroll
  for (int i = 0; i < 4; ++i) {
    const int r = m0 + tr * 4 + i;
    const int b = r >> 11;      // / 2048
    const int s = r & 2047;
#pragma unroll
    for (int j = 0; j < 4; ++j) {
      const int c = n0 + tc * 4 + j;
      const int h = c >> 6, d = c & 63;
      out[(((b * NH + h) * SS) + s) * HD + d] = acc[i][j] + bias[c];
    }
  }
}

// ---------------------------------------------------------------------------
// K2: attention core. One WG = one (b,h) and 8 query rows.
// scores (8x2048) live in exactly 64 KiB static LDS; q is read via
// wave-uniform global loads (compiler emits scalar loads, no LDS needed).
// Writes normalized attn directly to d_out, then computes ctx = P @ V.
// ---------------------------------------------------------------------------
__global__ __launch_bounds__(256) void attn_kernel(
    const float* __restrict__ qh, const float* __restrict__ kh, const float* __restrict__ vh,
    float* __restrict__ attn, float* __restrict__ ctx)
{
  __shared__ float sc[8][SS];   // 65536 B

  const int bh = blockIdx.y;          // 0..15  (b*NH + h)
  const int s0 = blockIdx.x * 8;      // query row block
  const int tid = threadIdx.x;

  const float* qp = qh + ((size_t)bh * SS + s0) * HD;   // 8 x 64
  const float* kp = kh + (size_t)bh * SS * HD;          // 2048 x 64
  const float* vp = vh + (size_t)bh * SS * HD;          // 2048 x 64

  // ---- Phase A: scores = q @ k^T / 8 -------------------------------------
  const float scale = 0.125f;
  for (int c0 = 0; c0 < SS; c0 += 512) {
    const int c = c0 + tid * 2;
    float acc0[8] = {};
    float acc1[8] = {};
#pragma unroll
    for (int d0 = 0; d0 < HD; d0 += 16) {
      float4 ka[4], kb[4];
#pragma unroll
      for (int i = 0; i < 4; ++i) {
        ka[i] = *(const float4*)&kp[c * HD + d0 + i * 4];
        kb[i] = *(const float4*)&kp[(c + 1) * HD + d0 + i * 4];
      }
#pragma unroll
      for (int r = 0; r < 8; ++r) {
        // wave-uniform address -> scalar loads, L1/sL1 resident (512 floats total)
        const float4 q0 = *(const float4*)&qp[r * HD + d0 + 0];
        const float4 q1 = *(const float4*)&qp[r * HD + d0 + 4];
        const float4 q2 = *(const float4*)&qp[r * HD + d0 + 8];
        const float4 q3 = *(const float4*)&qp[r * HD + d0 + 12];
        acc0[r] += q0.x * ka[0].x + q0.y * ka[0].y + q0.z * ka[0].z + q0.w * ka[0].w
                 + q1.x * ka[1].x + q1.y * ka[1].y + q1.z * ka[1].z + q1.w * ka[1].w
                 + q2.x * ka[2].x + q2.y * ka[2].y + q2.z * ka[2].z + q2.w * ka[2].w
                 + q3.x * ka[3].x + q3.y * ka[3].y + q3.z * ka[3].z + q3.w * ka[3].w;
        acc1[r] += q0.x * kb[0].x + q0.y * kb[0].y + q0.z * kb[0].z + q0.w * kb[0].w
                 + q1.x * kb[1].x + q1.y * kb[1].y + q1.z * kb[1].z + q1.w * kb[1].w
                 + q2.x * kb[2].x + q2.y * kb[2].y + q2.z * kb[2].z + q2.w * kb[2].w
                 + q3.x * kb[3].x + q3.y * kb[3].y + q3.z * kb[3].z + q3.w * kb[3].w;
      }
    }
#pragma unroll
    for (int r = 0; r < 8; ++r) {
      *(float2*)&sc[r][c] = make_float2(acc0[r] * scale, acc1[r] * scale);
    }
  }
  __syncthreads();

  // ---- Softmax: row r handled by half-wave (32 threads) ------------------
  {
    const int r  = tid >> 5;   // 0..7
    const int lg = tid & 31;

    float m = -1e30f;
    for (int c = lg * 4; c < SS; c += 128) {
      const float4 sv = *(const float4*)&sc[r][c];
      m = fmaxf(m, fmaxf(fmaxf(sv.x, sv.y), fmaxf(sv.z, sv.w)));
    }
#pragma unroll
    for (int off = 16; off; off >>= 1) m = fmaxf(m, __shfl_xor(m, off, 32));

    float l = 0.f;
    for (int c = lg * 4; c < SS; c += 128) {
      float4 sv = *(const float4*)&sc[r][c];
      sv.x = __expf(sv.x - m); sv.y = __expf(sv.y - m);
      sv.z = __expf(sv.z - m); sv.w = __expf(sv.w - m);
      *(float4*)&sc[r][c] = sv;
      l += sv.x + sv.y + sv.z + sv.w;
    }
#pragma unroll
    for (int off = 16; off; off >>= 1) l += __shfl_xor(l, off, 32);

    const float inv = 1.f / l;
    float* arow = attn + ((size_t)bh * SS + s0 + r) * SS;
    for (int c = lg * 4; c < SS; c += 128) {
      float4 sv = *(const float4*)&sc[r][c];
      sv.x *= inv; sv.y *= inv; sv.z *= inv; sv.w *= inv;
      *(float4*)&sc[r][c] = sv;
      *(float4*)&arow[c] = sv;
    }
  }
  __syncthreads();

  // ---- Phase B: ctx = P @ V ----------------------------------------------
  // threads: d2 = d-pair (0..31), tg = t-chunk (0..7, 256 t each)
  {
    const int d2 = tid & 31;
    const int tg = tid >> 5;
    const int dd = d2 * 2;
    float accv[8][2] = {};
    const int tbase = tg * 256;
    for (int t = tbase; t < tbase + 256; t += 4) {
      const float2 v0 = *(const float2*)&vp[(t + 0) * HD + dd];
      const float2 v1 = *(const float2*)&vp[(t + 1) * HD + dd];
      const float2 v2 = *(const float2*)&vp[(t + 2) * HD + dd];
      const float2 v3 = *(const float2*)&vp[(t + 3) * HD + dd];
#pragma unroll
      for (int r = 0; r < 8; ++r) {
        const float4 p = *(const float4*)&sc[r][t];
        accv[r][0] += p.x * v0.x + p.y * v1.x + p.z * v2.x + p.w * v3.x;
        accv[r][1] += p.x * v0.y + p.y * v1.y + p.z * v2.y + p.w * v3.y;
      }
    }
    __syncthreads();   // everyone done reading sc before we overwrite it

    float* pb = &sc[0][0];   // reuse as partial buffer [8 tg][8 r][64 d]
#pragma unroll
    for (int r = 0; r < 8; ++r) {
      pb[(tg * 8 + r) * HD + dd + 0] = accv[r][0];
      pb[(tg * 8 + r) * HD + dd + 1] = accv[r][1];
    }
    __syncthreads();

    for (int o = tid; o < 8 * HD; o += 256) {
      const int r = o >> 6, d = o & 63;
      float sum = 0.f;
#pragma unroll
      for (int g = 0; g < 8; ++g) sum += pb[(g * 8 + r) * HD + d];
      ctx[((size_t)bh * SS + s0 + r) * HD + d] = sum;
    }
  }
}

// ---------------------------------------------------------------------------
// K3: output projection. out = ctx @ Wo^T + bo  (ctx gathered from head layout)
// ---------------------------------------------------------------------------
__global__ __launch_bounds__(256) void out_proj_kernel(
    const float* __restrict__ ctx, const float* __restrict__ Wo, const float* __restrict__ bo,
    float* __restrict__ out)
{
  __shared__ float As[16][68];
  __shared__ float Bs[16][68];

  const int m0 = blockIdx.x * 64;
  const int n0 = blockIdx.y * 64;
  const int tid = threadIdx.x;
  const int tr = tid >> 4, tc = tid & 15;
  const int lr = tid >> 2, lk = (tid & 3) << 2;

  float acc[4][4] = {};

  for (int k0 = 0; k0 < DIM; k0 += 16) {
    const int r = m0 + lr;
    const int b = r >> 11, s = r & 2047;
    const int kq = k0 + lk;
    const int h = kq >> 6, d = kq & 63;
    const float4 av = *(const float4*)&ctx[(((b * NH + h) * SS) + s) * HD + d];
    const float4 wv = *(const float4*)&Wo[(n0 + lr) * DIM + kq];
    As[lk + 0][lr] = av.x; As[lk + 1][lr] = av.y; As[lk + 2][lr] = av.z; As[lk + 3][lr] = av.w;
    Bs[lk + 0][lr] = wv.x; Bs[lk + 1][lr] = wv.y; Bs[lk + 2][lr] = wv.z; Bs[lk + 3][lr] = wv.w;
    __syncthreads();
#pragma unroll
    for (int kk = 0; kk < 16; ++kk) {
      const float4 a4 = *(const float4*)&As[kk][tr * 4];
      const float4 b4 = *(const float4*)&Bs[kk][tc * 4];
      const float a[4] = {a4.x, a4.y, a4.z, a4.w};
      const float b[4] = {b4.x, b4.y, b4.z, b4.w};
#pragma unroll
      for (int i = 0; i < 4; ++i)
#pragma unroll
        for (int j = 0; j < 4; ++j) acc[i][j] += a[i] * b[j];
    }
    __syncthreads();
  }

#pragma unroll
  for (int i = 0; i < 4; ++i) {
    const int r = m0 + tr * 4 + i;
#pragma unroll
    for (int j = 0; j < 4; ++j) {
      const int c = n0 + tc * 4 + j;
      out[r * DIM + c] = acc[i][j] + bo[c];
    }
  }
}

// ---------------------------------------------------------------------------
extern "C" void kernel_launch(void* const* d_in, const int* in_sizes, int n_in,
                              void* d_out, int out_size, void* d_ws, size_t ws_size,
                              hipStream_t stream) {
  const float* q  = (const float*)d_in[0];
  const float* k  = (const float*)d_in[1];
  const float* v  = (const float*)d_in[2];
  const float* Wq = (const float*)d_in[3];
  const float* bq = (const float*)d_in[4];
  const float* Wk = (const float*)d_in[5];
  const float* bk = (const float*)d_in[6];
  const float* Wv = (const float*)d_in[7];
  const float* bv = (const float*)d_in[8];
  const float* Wo = (const float*)d_in[9];
  const float* bo = (const float*)d_in[10];

  float* out0 = (float*)d_out;                                    // [2,2048,512]
  float* attn = out0 + (size_t)NB * SS * DIM;                     // [2,8,2048,2048]

  const size_t HSZ = (size_t)NB * NH * SS * HD;                   // 2,097,152
  float* qh  = (float*)d_ws;
  float* kh  = qh + HSZ;
  float* vh  = kh + HSZ;
  float* ctx = vh + HSZ;

  dim3 g1(NB * SS / 64, DIM / 64, 3);
  qkv_proj_kernel<<<g1, 256, 0, stream>>>(q, k, v, Wq, bq, Wk, bk, Wv, bv, qh, kh, vh);

  dim3 g2(SS / 8, NB * NH);
  attn_kernel<<<g2, 256, 0, stream>>>(qh, kh, vh, attn, ctx);

  dim3 g3(NB * SS / 64, DIM / 64);
  out_proj_kernel<<<g3, 256, 0, stream>>>(ctx, Wo, bo, out0);
}

// Round 2
// 220.415 us; speedup vs baseline: 5.0118x; 5.0118x over previous
//
#include <hip/hip_runtime.h>
#include <math.h>

#define DIM 512
#define NH 8
#define HD 64
#define SS 2048
#define NB 2

typedef __bf16 bf16;
typedef __attribute__((ext_vector_type(8))) __bf16 bf16x8;
typedef __attribute__((ext_vector_type(4))) __bf16 bf16x4;
typedef __attribute__((ext_vector_type(4))) float f32x4;

// ---------------------------------------------------------------------------
// K1: QKV projection (fp32 math), outputs bf16 in head layout [B,H,S,HD].
// q output is pre-scaled by 1/sqrt(HD) = 0.125 (exact power of 2).
// ---------------------------------------------------------------------------
__global__ __launch_bounds__(256) void qkv_proj_kernel(
    const float* __restrict__ xq, const float* __restrict__ xk, const float* __restrict__ xv,
    const float* __restrict__ Wq, const float* __restrict__ bq,
    const float* __restrict__ Wk, const float* __restrict__ bk,
    const float* __restrict__ Wv, const float* __restrict__ bv,
    bf16* __restrict__ qh, bf16* __restrict__ kh, bf16* __restrict__ vh)
{
  const int which = blockIdx.z;
  const float* A    = (which == 0) ? xq : (which == 1) ? xk : xv;
  const float* W    = (which == 0) ? Wq : (which == 1) ? Wk : Wv;
  const float* bias = (which == 0) ? bq : (which == 1) ? bk : bv;
  bf16* out         = (which == 0) ? qh : (which == 1) ? kh : vh;
  const float oscale = (which == 0) ? 0.125f : 1.0f;

  __shared__ float As[16][68];
  __shared__ float Bs[16][68];

  const int m0 = blockIdx.x * 64;
  const int n0 = blockIdx.y * 64;
  const int tid = threadIdx.x;
  const int tr = tid >> 4, tc = tid & 15;
  const int lr = tid >> 2, lk = (tid & 3) << 2;

  float acc[4][4] = {};

  for (int k0 = 0; k0 < DIM; k0 += 16) {
    const float4 av = *(const float4*)&A[(m0 + lr) * DIM + k0 + lk];
    const float4 wv = *(const float4*)&W[(n0 + lr) * DIM + k0 + lk];
    As[lk + 0][lr] = av.x; As[lk + 1][lr] = av.y; As[lk + 2][lr] = av.z; As[lk + 3][lr] = av.w;
    Bs[lk + 0][lr] = wv.x; Bs[lk + 1][lr] = wv.y; Bs[lk + 2][lr] = wv.z; Bs[lk + 3][lr] = wv.w;
    __syncthreads();
#pragma unroll
    for (int kk = 0; kk < 16; ++kk) {
      const float4 a4 = *(const float4*)&As[kk][tr * 4];
      const float4 b4 = *(const float4*)&Bs[kk][tc * 4];
      const float a[4] = {a4.x, a4.y, a4.z, a4.w};
      const float b[4] = {b4.x, b4.y, b4.z, b4.w};
#pragma unroll
      for (int i = 0; i < 4; ++i)
#pragma unroll
        for (int j = 0; j < 4; ++j) acc[i][j] += a[i] * b[j];
    }
    __syncthreads();
  }

  const int h = n0 >> 6;   // n0 is a multiple of 64 -> head fixed per block
#pragma unroll
  for (int i = 0; i < 4; ++i) {
    const int r = m0 + tr * 4 + i;
    const int b = r >> 11;
    const int s = r & 2047;
    bf16x4 o;
#pragma unroll
    for (int j = 0; j < 4; ++j) {
      const int c = n0 + tc * 4 + j;
      o[j] = (bf16)((acc[i][j] + bias[c]) * oscale);
    }
    *(bf16x4*)&out[(((size_t)(b * NH + h) * SS) + s) * HD + tc * 4] = o;
  }
}

// ---------------------------------------------------------------------------
// K2: MFMA attention. One WG = one (b,h) x 64 q-rows (16 per wave).
// Pass 1: S = QK^T tiles (bf16 MFMA), online row max/sum. Pass 2: recompute S,
// write normalized P (fp32) to d_out, accumulate ctx = P V via MFMA.
//
// mfma_f32_16x16x32_bf16 layouts (gfx950):
//   A[m][k]: m = lane&15, k = 8*(lane>>4) + j
//   B[k][n]: n = lane&15, k = 8*(lane>>4) + j
//   D[m][n]: n = lane&15, m = 4*(lane>>4) + reg
// ---------------------------------------------------------------------------
__global__ __launch_bounds__(256) void attn_kernel(
    const bf16* __restrict__ qh, const bf16* __restrict__ kh, const bf16* __restrict__ vh,
    float* __restrict__ attn, float* __restrict__ ctx)
{
  __shared__ bf16 Ks[128][72];      // K tile [t][d], +8 pad
  __shared__ bf16 Vt[64][136];      // V tile transposed [d][t], +8 pad
  __shared__ bf16 Ps[4][16][136];   // per-wave P transpose buffer [q][t]

  const int bh = blockIdx.y;
  const int q0 = blockIdx.x * 64;
  const int tid = threadIdx.x;
  const int w   = tid >> 6;
  const int l   = tid & 63;
  const int l16 = l & 15;
  const int lg  = l >> 4;

  const bf16* qp = qh + (size_t)bh * SS * HD;
  const bf16* kp = kh + (size_t)bh * SS * HD;
  const bf16* vp = vh + (size_t)bh * SS * HD;

  // Q fragments for this wave's 16 rows (q pre-scaled by 0.125 in K1)
  const int qrow = q0 + w * 16 + l16;
  const bf16x8 qf0 = *(const bf16x8*)&qp[(size_t)qrow * HD + lg * 8];
  const bf16x8 qf1 = *(const bf16x8*)&qp[(size_t)qrow * HD + 32 + lg * 8];

  float m_run[4], l_run[4];
#pragma unroll
  for (int r = 0; r < 4; ++r) { m_run[r] = -1e30f; l_run[r] = 0.f; }

  // ---------------- pass 1: row max & sum ----------------
  for (int t0 = 0; t0 < SS; t0 += 128) {
    __syncthreads();
    {  // stage K tile: thread -> (row tid>>1, half tid&1)
      const int r = tid >> 1, hh = tid & 1;
      const bf16* src = &kp[(size_t)(t0 + r) * HD + hh * 32];
      bf16* dst = &Ks[r][hh * 32];
#pragma unroll
      for (int i = 0; i < 4; ++i) ((bf16x8*)dst)[i] = ((const bf16x8*)src)[i];
    }
    __syncthreads();

    f32x4 accS[8];
#pragma unroll
    for (int n = 0; n < 8; ++n) {
      const bf16x8 kf0 = *(const bf16x8*)&Ks[n * 16 + l16][lg * 8];
      const bf16x8 kf1 = *(const bf16x8*)&Ks[n * 16 + l16][32 + lg * 8];
      f32x4 acc = {0.f, 0.f, 0.f, 0.f};
      acc = __builtin_amdgcn_mfma_f32_16x16x32_bf16(qf0, kf0, acc, 0, 0, 0);
      acc = __builtin_amdgcn_mfma_f32_16x16x32_bf16(qf1, kf1, acc, 0, 0, 0);
      accS[n] = acc;
    }
#pragma unroll
    for (int r = 0; r < 4; ++r) {
      float tmax = accS[0][r];
#pragma unroll
      for (int n = 1; n < 8; ++n) tmax = fmaxf(tmax, accS[n][r]);
      const float nm = fmaxf(m_run[r], tmax);
      float sum = 0.f;
#pragma unroll
      for (int n = 0; n < 8; ++n) sum += __expf(accS[n][r] - nm);
      l_run[r] = l_run[r] * __expf(m_run[r] - nm) + sum;
      m_run[r] = nm;
    }
  }

  // reduce (m,l) across the 16 lanes that share the same 4 rows
#pragma unroll
  for (int r = 0; r < 4; ++r) {
    float m = m_run[r], ls = l_run[r];
#pragma unroll
    for (int off = 1; off < 16; off <<= 1) {
      const float m2 = __shfl_xor(m, off);
      const float l2 = __shfl_xor(ls, off);
      const float nm = fmaxf(m, m2);
      ls = ls * __expf(m - nm) + l2 * __expf(m2 - nm);
      m = nm;
    }
    m_run[r] = m;
    l_run[r] = 1.f / ls;   // store inverse sum
  }

  // ---------------- pass 2: P write + P·V ----------------
  f32x4 accC[4];
#pragma unroll
  for (int dt = 0; dt < 4; ++dt) accC[dt] = (f32x4){0.f, 0.f, 0.f, 0.f};

  float* arow_base = attn + ((size_t)(bh * SS + q0 + w * 16)) * SS;

  for (int t0 = 0; t0 < SS; t0 += 128) {
    __syncthreads();
    if (tid < 128) {   // waves 0-1: stage V transposed
      const int r = tid;
      bf16 vrow[64];
      const bf16* src = &vp[(size_t)(t0 + r) * HD];
#pragma unroll
      for (int i = 0; i < 8; ++i) ((bf16x8*)vrow)[i] = ((const bf16x8*)src)[i];
#pragma unroll
      for (int d = 0; d < 64; ++d) Vt[d][r] = vrow[d];
    } else {           // waves 2-3: stage K
      const int r = tid - 128;
      const bf16* src = &kp[(size_t)(t0 + r) * HD];
      bf16* dst = &Ks[r][0];
#pragma unroll
      for (int i = 0; i < 8; ++i) ((bf16x8*)dst)[i] = ((const bf16x8*)src)[i];
    }
    __syncthreads();

    f32x4 accS[8];
#pragma unroll
    for (int n = 0; n < 8; ++n) {
      const bf16x8 kf0 = *(const bf16x8*)&Ks[n * 16 + l16][lg * 8];
      const bf16x8 kf1 = *(const bf16x8*)&Ks[n * 16 + l16][32 + lg * 8];
      f32x4 acc = {0.f, 0.f, 0.f, 0.f};
      acc = __builtin_amdgcn_mfma_f32_16x16x32_bf16(qf0, kf0, acc, 0, 0, 0);
      acc = __builtin_amdgcn_mfma_f32_16x16x32_bf16(qf1, kf1, acc, 0, 0, 0);
      accS[n] = acc;
    }

    // P = exp(S - m) * inv_l ; write fp32 attn + bf16 transpose buffer
#pragma unroll
    for (int n = 0; n < 8; ++n) {
#pragma unroll
      for (int r = 0; r < 4; ++r) {
        const int row = lg * 4 + r;
        const float p = __expf(accS[n][r] - m_run[r]) * l_run[r];
        arow_base[(size_t)row * SS + t0 + n * 16 + l16] = p;
        Ps[w][row][n * 16 + l16] = (bf16)p;
      }
    }

    // ctx += P_tile(16x128) @ V_tile(128x64)
#pragma unroll
    for (int ts = 0; ts < 4; ++ts) {
      const bf16x8 pa = *(const bf16x8*)&Ps[w][l16][ts * 32 + lg * 8];
#pragma unroll
      for (int dt = 0; dt < 4; ++dt) {
        const bf16x8 vb = *(const bf16x8*)&Vt[dt * 16 + l16][ts * 32 + lg * 8];
        accC[dt] = __builtin_amdgcn_mfma_f32_16x16x32_bf16(pa, vb, accC[dt], 0, 0, 0);
      }
    }
  }

#pragma unroll
  for (int dt = 0; dt < 4; ++dt)
#pragma unroll
    for (int r = 0; r < 4; ++r)
      ctx[((size_t)(bh * SS + q0 + w * 16 + lg * 4 + r)) * HD + dt * 16 + l16] = accC[dt][r];
}

// ---------------------------------------------------------------------------
// K3: output projection. out = ctx @ Wo^T + bo (ctx fp32, head layout)
// ---------------------------------------------------------------------------
__global__ __launch_bounds__(256) void out_proj_kernel(
    const float* __restrict__ ctx, const float* __restrict__ Wo, const float* __restrict__ bo,
    float* __restrict__ out)
{
  __shared__ float As[16][68];
  __shared__ float Bs[16][68];

  const int m0 = blockIdx.x * 64;
  const int n0 = blockIdx.y * 64;
  const int tid = threadIdx.x;
  const int tr = tid >> 4, tc = tid & 15;
  const int lr = tid >> 2, lk = (tid & 3) << 2;

  float acc[4][4] = {};

  for (int k0 = 0; k0 < DIM; k0 += 16) {
    const int r = m0 + lr;
    const int b = r >> 11, s = r & 2047;
    const int kq = k0 + lk;
    const int h = kq >> 6, d = kq & 63;
    const float4 av = *(const float4*)&ctx[(((size_t)(b * NH + h) * SS) + s) * HD + d];
    const float4 wv = *(const float4*)&Wo[(n0 + lr) * DIM + kq];
    As[lk + 0][lr] = av.x; As[lk + 1][lr] = av.y; As[lk + 2][lr] = av.z; As[lk + 3][lr] = av.w;
    Bs[lk + 0][lr] = wv.x; Bs[lk + 1][lr] = wv.y; Bs[lk + 2][lr] = wv.z; Bs[lk + 3][lr] = wv.w;
    __syncthreads();
#pragma unroll
    for (int kk = 0; kk < 16; ++kk) {
      const float4 a4 = *(const float4*)&As[kk][tr * 4];
      const float4 b4 = *(const float4*)&Bs[kk][tc * 4];
      const float a[4] = {a4.x, a4.y, a4.z, a4.w};
      const float b[4] = {b4.x, b4.y, b4.z, b4.w};
#pragma unroll
      for (int i = 0; i < 4; ++i)
#pragma unroll
        for (int j = 0; j < 4; ++j) acc[i][j] += a[i] * b[j];
    }
    __syncthreads();
  }

#pragma unroll
  for (int i = 0; i < 4; ++i) {
    const int r = m0 + tr * 4 + i;
#pragma unroll
    for (int j = 0; j < 4; ++j) {
      const int c = n0 + tc * 4 + j;
      out[(size_t)r * DIM + c] = acc[i][j] + bo[c];
    }
  }
}

// ---------------------------------------------------------------------------
extern "C" void kernel_launch(void* const* d_in, const int* in_sizes, int n_in,
                              void* d_out, int out_size, void* d_ws, size_t ws_size,
                              hipStream_t stream) {
  const float* q  = (const float*)d_in[0];
  const float* k  = (const float*)d_in[1];
  const float* v  = (const float*)d_in[2];
  const float* Wq = (const float*)d_in[3];
  const float* bq = (const float*)d_in[4];
  const float* Wk = (const float*)d_in[5];
  const float* bk = (const float*)d_in[6];
  const float* Wv = (const float*)d_in[7];
  const float* bv = (const float*)d_in[8];
  const float* Wo = (const float*)d_in[9];
  const float* bo = (const float*)d_in[10];

  float* out0 = (float*)d_out;                     // [2,2048,512]
  float* attn = out0 + (size_t)NB * SS * DIM;      // [2,8,2048,2048]

  const size_t HSZ = (size_t)NB * NH * SS * HD;    // 2,097,152
  bf16* qh   = (bf16*)d_ws;
  bf16* kh   = qh + HSZ;
  bf16* vh   = kh + HSZ;
  float* ctx = (float*)(vh + HSZ);                 // fp32, 8 MB

  dim3 g1(NB * SS / 64, DIM / 64, 3);
  qkv_proj_kernel<<<g1, 256, 0, stream>>>(q, k, v, Wq, bq, Wk, bk, Wv, bv, qh, kh, vh);

  dim3 g2(SS / 64, NB * NH);
  attn_kernel<<<g2, 256, 0, stream>>>(qh, kh, vh, attn, ctx);

  dim3 g3(NB * SS / 64, DIM / 64);
  out_proj_kernel<<<g3, 256, 0, stream>>>(ctx, Wo, bo, out0);
}

// Round 3
// 148.562 us; speedup vs baseline: 7.4358x; 1.4837x over previous
//
#include <hip/hip_runtime.h>
#include <math.h>

#define DIM 512
#define NH 8
#define HD 64
#define SS 2048
#define NB 2

typedef __bf16 bf16;
typedef __attribute__((ext_vector_type(8))) __bf16 bf16x8;
typedef __attribute__((ext_vector_type(4))) float f32x4;

// convert 8 consecutive floats -> bf16x8
__device__ inline bf16x8 cvt8(const float* s) {
  bf16x8 o;
#pragma unroll
  for (int i = 0; i < 8; ++i) o[i] = (bf16)s[i];
  return o;
}

// ---------------------------------------------------------------------------
// K1: QKV projection, bf16 MFMA.  y = x @ W^T + b -> bf16 head layout [B,H,S,HD].
// q output pre-scaled by 0.125. Tile 128x64, BK=64, 4 waves (2x2).
// ---------------------------------------------------------------------------
__global__ __launch_bounds__(256) void qkv_proj_kernel(
    const float* __restrict__ xq, const float* __restrict__ xk, const float* __restrict__ xv,
    const float* __restrict__ Wq, const float* __restrict__ bq,
    const float* __restrict__ Wk, const float* __restrict__ bk,
    const float* __restrict__ Wv, const float* __restrict__ bv,
    bf16* __restrict__ qh, bf16* __restrict__ kh, bf16* __restrict__ vh)
{
  const int which = blockIdx.z;
  const float* A    = (which == 0) ? xq : (which == 1) ? xk : xv;
  const float* W    = (which == 0) ? Wq : (which == 1) ? Wk : Wv;
  const float* bias = (which == 0) ? bq : (which == 1) ? bk : bv;
  bf16* out         = (which == 0) ? qh : (which == 1) ? kh : vh;
  const float oscale = (which == 0) ? 0.125f : 1.0f;

  __shared__ bf16 As[128][72];   // [m][k], +8 pad (144B row stride, 16B aligned)
  __shared__ bf16 Bs[64][72];    // [n][k]

  const int m0 = blockIdx.x * 128;
  const int n0 = blockIdx.y * 64;      // head = blockIdx.y (HD==BN==64)
  const int tid = threadIdx.x;
  const int w = tid >> 6, l = tid & 63;
  const int l16 = l & 15, lg = l >> 4;
  const int wm = w >> 1, wn = w & 1;

  f32x4 acc[4][2];
#pragma unroll
  for (int mf = 0; mf < 4; ++mf)
#pragma unroll
    for (int nf = 0; nf < 2; ++nf) acc[mf][nf] = (f32x4){0.f, 0.f, 0.f, 0.f};

  for (int k0 = 0; k0 < DIM; k0 += 64) {
    __syncthreads();
    {  // stage A: 128 rows x 64 k; thread -> (row tid>>1, half tid&1)
      const int r = tid >> 1, hf = (tid & 1) * 32;
      const float* src = &A[(size_t)(m0 + r) * DIM + k0 + hf];
      bf16* dst = &As[r][hf];
#pragma unroll
      for (int i = 0; i < 4; ++i) ((bf16x8*)dst)[i] = cvt8(src + i * 8);
    }
    if (tid < 128) {  // stage B (W rows): 64 rows x 64 k
      const int r = tid >> 1, hf = (tid & 1) * 32;
      const float* src = &W[(size_t)(n0 + r) * DIM + k0 + hf];
      bf16* dst = &Bs[r][hf];
#pragma unroll
      for (int i = 0; i < 4; ++i) ((bf16x8*)dst)[i] = cvt8(src + i * 8);
    }
    __syncthreads();

#pragma unroll
    for (int kk = 0; kk < 2; ++kk) {
      bf16x8 bfr[2];
      bfr[0] = *(const bf16x8*)&Bs[wn * 32 + l16][kk * 32 + lg * 8];
      bfr[1] = *(const bf16x8*)&Bs[wn * 32 + 16 + l16][kk * 32 + lg * 8];
#pragma unroll
      for (int mf = 0; mf < 4; ++mf) {
        const bf16x8 af = *(const bf16x8*)&As[wm * 64 + mf * 16 + l16][kk * 32 + lg * 8];
        acc[mf][0] = __builtin_amdgcn_mfma_f32_16x16x32_bf16(af, bfr[0], acc[mf][0], 0, 0, 0);
        acc[mf][1] = __builtin_amdgcn_mfma_f32_16x16x32_bf16(af, bfr[1], acc[mf][1], 0, 0, 0);
      }
    }
  }

  const int h = blockIdx.y;
#pragma unroll
  for (int mf = 0; mf < 4; ++mf) {
#pragma unroll
    for (int nf = 0; nf < 2; ++nf) {
      const int d = wn * 32 + nf * 16 + l16;
#pragma unroll
      for (int ri = 0; ri < 4; ++ri) {
        const int row = m0 + wm * 64 + mf * 16 + lg * 4 + ri;
        const int b = row >> 11, s = row & 2047;
        out[((size_t)(b * NH + h) * SS + s) * HD + d] =
            (bf16)((acc[mf][nf][ri] + bias[n0 + d]) * oscale);
      }
    }
  }
}

// ---------------------------------------------------------------------------
// K2: MFMA attention (unchanged math). ctx now written bf16, flat [B,S,DIM].
// ---------------------------------------------------------------------------
__global__ __launch_bounds__(256) void attn_kernel(
    const bf16* __restrict__ qh, const bf16* __restrict__ kh, const bf16* __restrict__ vh,
    float* __restrict__ attn, bf16* __restrict__ ctx)
{
  __shared__ bf16 Ks[128][72];
  __shared__ bf16 Vt[64][136];
  __shared__ bf16 Ps[4][16][136];

  const int bh = blockIdx.y;
  const int q0 = blockIdx.x * 64;
  const int tid = threadIdx.x;
  const int w   = tid >> 6;
  const int l   = tid & 63;
  const int l16 = l & 15;
  const int lg  = l >> 4;

  const bf16* qp = qh + (size_t)bh * SS * HD;
  const bf16* kp = kh + (size_t)bh * SS * HD;
  const bf16* vp = vh + (size_t)bh * SS * HD;

  const int qrow = q0 + w * 16 + l16;
  const bf16x8 qf0 = *(const bf16x8*)&qp[(size_t)qrow * HD + lg * 8];
  const bf16x8 qf1 = *(const bf16x8*)&qp[(size_t)qrow * HD + 32 + lg * 8];

  float m_run[4], l_run[4];
#pragma unroll
  for (int r = 0; r < 4; ++r) { m_run[r] = -1e30f; l_run[r] = 0.f; }

  // ---------------- pass 1: row max & sum ----------------
  for (int t0 = 0; t0 < SS; t0 += 128) {
    __syncthreads();
    {
      const int r = tid >> 1, hh = tid & 1;
      const bf16* src = &kp[(size_t)(t0 + r) * HD + hh * 32];
      bf16* dst = &Ks[r][hh * 32];
#pragma unroll
      for (int i = 0; i < 4; ++i) ((bf16x8*)dst)[i] = ((const bf16x8*)src)[i];
    }
    __syncthreads();

    f32x4 accS[8];
#pragma unroll
    for (int n = 0; n < 8; ++n) {
      const bf16x8 kf0 = *(const bf16x8*)&Ks[n * 16 + l16][lg * 8];
      const bf16x8 kf1 = *(const bf16x8*)&Ks[n * 16 + l16][32 + lg * 8];
      f32x4 acc = {0.f, 0.f, 0.f, 0.f};
      acc = __builtin_amdgcn_mfma_f32_16x16x32_bf16(qf0, kf0, acc, 0, 0, 0);
      acc = __builtin_amdgcn_mfma_f32_16x16x32_bf16(qf1, kf1, acc, 0, 0, 0);
      accS[n] = acc;
    }
#pragma unroll
    for (int r = 0; r < 4; ++r) {
      float tmax = accS[0][r];
#pragma unroll
      for (int n = 1; n < 8; ++n) tmax = fmaxf(tmax, accS[n][r]);
      const float nm = fmaxf(m_run[r], tmax);
      float sum = 0.f;
#pragma unroll
      for (int n = 0; n < 8; ++n) sum += __expf(accS[n][r] - nm);
      l_run[r] = l_run[r] * __expf(m_run[r] - nm) + sum;
      m_run[r] = nm;
    }
  }

#pragma unroll
  for (int r = 0; r < 4; ++r) {
    float m = m_run[r], ls = l_run[r];
#pragma unroll
    for (int off = 1; off < 16; off <<= 1) {
      const float m2 = __shfl_xor(m, off);
      const float l2 = __shfl_xor(ls, off);
      const float nm = fmaxf(m, m2);
      ls = ls * __expf(m - nm) + l2 * __expf(m2 - nm);
      m = nm;
    }
    m_run[r] = m;
    l_run[r] = 1.f / ls;
  }

  // ---------------- pass 2: P write + P·V ----------------
  f32x4 accC[4];
#pragma unroll
  for (int dt = 0; dt < 4; ++dt) accC[dt] = (f32x4){0.f, 0.f, 0.f, 0.f};

  float* arow_base = attn + ((size_t)(bh * SS + q0 + w * 16)) * SS;

  for (int t0 = 0; t0 < SS; t0 += 128) {
    __syncthreads();
    if (tid < 128) {
      const int r = tid;
      bf16 vrow[64];
      const bf16* src = &vp[(size_t)(t0 + r) * HD];
#pragma unroll
      for (int i = 0; i < 8; ++i) ((bf16x8*)vrow)[i] = ((const bf16x8*)src)[i];
#pragma unroll
      for (int d = 0; d < 64; ++d) Vt[d][r] = vrow[d];
    } else {
      const int r = tid - 128;
      const bf16* src = &kp[(size_t)(t0 + r) * HD];
      bf16* dst = &Ks[r][0];
#pragma unroll
      for (int i = 0; i < 8; ++i) ((bf16x8*)dst)[i] = ((const bf16x8*)src)[i];
    }
    __syncthreads();

    f32x4 accS[8];
#pragma unroll
    for (int n = 0; n < 8; ++n) {
      const bf16x8 kf0 = *(const bf16x8*)&Ks[n * 16 + l16][lg * 8];
      const bf16x8 kf1 = *(const bf16x8*)&Ks[n * 16 + l16][32 + lg * 8];
      f32x4 acc = {0.f, 0.f, 0.f, 0.f};
      acc = __builtin_amdgcn_mfma_f32_16x16x32_bf16(qf0, kf0, acc, 0, 0, 0);
      acc = __builtin_amdgcn_mfma_f32_16x16x32_bf16(qf1, kf1, acc, 0, 0, 0);
      accS[n] = acc;
    }

#pragma unroll
    for (int n = 0; n < 8; ++n) {
#pragma unroll
      for (int r = 0; r < 4; ++r) {
        const int row = lg * 4 + r;
        const float p = __expf(accS[n][r] - m_run[r]) * l_run[r];
        arow_base[(size_t)row * SS + t0 + n * 16 + l16] = p;
        Ps[w][row][n * 16 + l16] = (bf16)p;
      }
    }

#pragma unroll
    for (int ts = 0; ts < 4; ++ts) {
      const bf16x8 pa = *(const bf16x8*)&Ps[w][l16][ts * 32 + lg * 8];
#pragma unroll
      for (int dt = 0; dt < 4; ++dt) {
        const bf16x8 vb = *(const bf16x8*)&Vt[dt * 16 + l16][ts * 32 + lg * 8];
        accC[dt] = __builtin_amdgcn_mfma_f32_16x16x32_bf16(pa, vb, accC[dt], 0, 0, 0);
      }
    }
  }

  const int b = bh >> 3, h = bh & 7;
#pragma unroll
  for (int dt = 0; dt < 4; ++dt)
#pragma unroll
    for (int r = 0; r < 4; ++r) {
      const int s = q0 + w * 16 + lg * 4 + r;
      ctx[((size_t)b * SS + s) * DIM + h * HD + dt * 16 + l16] = (bf16)accC[dt][r];
    }
}

// ---------------------------------------------------------------------------
// K3: output projection, bf16 MFMA. out = ctx @ Wo^T + bo (fp32 out).
// ctx is bf16 flat [4096][512]. Tile 128x64, BK=64.
// ---------------------------------------------------------------------------
__global__ __launch_bounds__(256) void out_proj_kernel(
    const bf16* __restrict__ ctx, const float* __restrict__ Wo, const float* __restrict__ bo,
    float* __restrict__ out)
{
  __shared__ bf16 As[128][72];
  __shared__ bf16 Bs[64][72];

  const int m0 = blockIdx.x * 128;
  const int n0 = blockIdx.y * 64;
  const int tid = threadIdx.x;
  const int w = tid >> 6, l = tid & 63;
  const int l16 = l & 15, lg = l >> 4;
  const int wm = w >> 1, wn = w & 1;

  f32x4 acc[4][2];
#pragma unroll
  for (int mf = 0; mf < 4; ++mf)
#pragma unroll
    for (int nf = 0; nf < 2; ++nf) acc[mf][nf] = (f32x4){0.f, 0.f, 0.f, 0.f};

  for (int k0 = 0; k0 < DIM; k0 += 64) {
    __syncthreads();
    {  // stage A (already bf16, contiguous)
      const int r = tid >> 1, hf = (tid & 1) * 32;
      const bf16* src = &ctx[(size_t)(m0 + r) * DIM + k0 + hf];
      bf16* dst = &As[r][hf];
#pragma unroll
      for (int i = 0; i < 4; ++i) ((bf16x8*)dst)[i] = ((const bf16x8*)src)[i];
    }
    if (tid < 128) {
      const int r = tid >> 1, hf = (tid & 1) * 32;
      const float* src = &Wo[(size_t)(n0 + r) * DIM + k0 + hf];
      bf16* dst = &Bs[r][hf];
#pragma unroll
      for (int i = 0; i < 4; ++i) ((bf16x8*)dst)[i] = cvt8(src + i * 8);
    }
    __syncthreads();

#pragma unroll
    for (int kk = 0; kk < 2; ++kk) {
      bf16x8 bfr[2];
      bfr[0] = *(const bf16x8*)&Bs[wn * 32 + l16][kk * 32 + lg * 8];
      bfr[1] = *(const bf16x8*)&Bs[wn * 32 + 16 + l16][kk * 32 + lg * 8];
#pragma unroll
      for (int mf = 0; mf < 4; ++mf) {
        const bf16x8 af = *(const bf16x8*)&As[wm * 64 + mf * 16 + l16][kk * 32 + lg * 8];
        acc[mf][0] = __builtin_amdgcn_mfma_f32_16x16x32_bf16(af, bfr[0], acc[mf][0], 0, 0, 0);
        acc[mf][1] = __builtin_amdgcn_mfma_f32_16x16x32_bf16(af, bfr[1], acc[mf][1], 0, 0, 0);
      }
    }
  }

#pragma unroll
  for (int mf = 0; mf < 4; ++mf) {
#pragma unroll
    for (int nf = 0; nf < 2; ++nf) {
      const int c = n0 + wn * 32 + nf * 16 + l16;
#pragma unroll
      for (int ri = 0; ri < 4; ++ri) {
        const int row = m0 + wm * 64 + mf * 16 + lg * 4 + ri;
        out[(size_t)row * DIM + c] = acc[mf][nf][ri] + bo[c];
      }
    }
  }
}

// ---------------------------------------------------------------------------
extern "C" void kernel_launch(void* const* d_in, const int* in_sizes, int n_in,
                              void* d_out, int out_size, void* d_ws, size_t ws_size,
                              hipStream_t stream) {
  const float* q  = (const float*)d_in[0];
  const float* k  = (const float*)d_in[1];
  const float* v  = (const float*)d_in[2];
  const float* Wq = (const float*)d_in[3];
  const float* bq = (const float*)d_in[4];
  const float* Wk = (const float*)d_in[5];
  const float* bk = (const float*)d_in[6];
  const float* Wv = (const float*)d_in[7];
  const float* bv = (const float*)d_in[8];
  const float* Wo = (const float*)d_in[9];
  const float* bo = (const float*)d_in[10];

  float* out0 = (float*)d_out;                     // [2,2048,512] fp32
  float* attn = out0 + (size_t)NB * SS * DIM;      // [2,8,2048,2048] fp32

  const size_t HSZ = (size_t)NB * NH * SS * HD;    // 2,097,152
  bf16* qh  = (bf16*)d_ws;
  bf16* kh  = qh + HSZ;
  bf16* vh  = kh + HSZ;
  bf16* ctx = vh + HSZ;                            // bf16 flat [B,S,DIM], 4 MB

  dim3 g1(NB * SS / 128, DIM / 64, 3);
  qkv_proj_kernel<<<g1, 256, 0, stream>>>(q, k, v, Wq, bq, Wk, bk, Wv, bv, qh, kh, vh);

  dim3 g2(SS / 64, NB * NH);
  attn_kernel<<<g2, 256, 0, stream>>>(qh, kh, vh, attn, ctx);

  dim3 g3(NB * SS / 128, DIM / 64);
  out_proj_kernel<<<g3, 256, 0, stream>>>(ctx, Wo, bo, out0);
}